// Round 6
// baseline (220.862 us; speedup 1.0000x reference)
//
#include <hip/hip_runtime.h>
#include <cstdint>
#include <cstddef>

#define DMODEL 1024
#define NHEADS 16
#define DKH    64
#define SEQT   2048
#define NBATCH 2
#define MTOT   (NBATCH*SEQT)   // 4096

// 0.125 * log2(e): folds sm_scale and the exp->exp2 conversion into Q.
#define QSCALE 0.1803368801111204f

using h16   = _Float16;
using h16x2 = __attribute__((ext_vector_type(2))) h16;
using h16x4 = __attribute__((ext_vector_type(4))) h16;
using h16x8 = __attribute__((ext_vector_type(8))) h16;
using f32x4 = __attribute__((ext_vector_type(4))) float;
using fp16x2_native = __attribute__((ext_vector_type(2))) __fp16;

using as1_void = __attribute__((address_space(1))) void;
using as3_void = __attribute__((address_space(3))) void;

__device__ __forceinline__ void gll16(void* lds, const void* g) {
  __builtin_amdgcn_global_load_lds((const as1_void*)g, (as3_void*)lds, 16, 0, 0);
}

__device__ __forceinline__ h16x2 pkrtz(float a, float b) {
  fp16x2_native t = __builtin_amdgcn_cvt_pkrtz(a, b);
  h16x2 r; r[0] = (h16)t[0]; r[1] = (h16)t[1]; return r;
}

__device__ __forceinline__ h16x4 cvt4(const float4 v) {
  h16x4 o; o[0] = (h16)v.x; o[1] = (h16)v.y; o[2] = (h16)v.z; o[3] = (h16)v.w; return o;
}

// ---------------------------------------------------------------- prep ----
__global__ void prep_kernel(const float4* __restrict__ x,
                            const float4* __restrict__ Wq, const float4* __restrict__ Wk,
                            const float4* __restrict__ Wv, const float4* __restrict__ Wo,
                            h16x4* __restrict__ xb,
                            h16x4* __restrict__ wqb, h16x4* __restrict__ wkb,
                            h16x4* __restrict__ wvb, h16x4* __restrict__ wob,
                            float* __restrict__ ctab, float* __restrict__ stab) {
  const int tid  = blockIdx.x * blockDim.x + threadIdx.x;
  const int nthr = gridDim.x * blockDim.x;
  const int NX4 = MTOT * DMODEL / 4;
  const int NW4 = DMODEL * DMODEL / 4;
  for (int i = tid; i < NX4; i += nthr) xb[i] = cvt4(x[i]);
  for (int i = tid; i < NW4; i += nthr) {
    wqb[i] = cvt4(Wq[i]);
    wkb[i] = cvt4(Wk[i]);
    wvb[i] = cvt4(Wv[i]);
    wob[i] = cvt4(Wo[i]);
  }
  for (int i = tid; i < SEQT * 32; i += nthr) {
    const int t = i >> 5, fi = i & 31;
    float inv = __expf(-0.28782313662425575f * (float)fi);
    float ang = (float)t * inv;
    float s, c;
    sincosf(ang, &s, &c);
    ctab[i] = c; stab[i] = s;
  }
}

// --------------------------------------------------- 128x128 B^T GEMM ----
__device__ __forceinline__ void gemm128_bt(const h16* __restrict__ A, const h16* __restrict__ Bt,
                                           int m0, int n0, h16* Al, h16* Bl, f32x4 acc[4][4]) {
  const int tid  = threadIdx.x;
  const int lane = tid & 63;
  const int wv   = tid >> 6;
  const int wm = (wv >> 1) * 64, wn = (wv & 1) * 64;
  const int lr = lane & 15, lk = (lane >> 4) * 8;
  const int srow = tid >> 2, scol = (tid & 3) * 8;
  const h16* a0 = A  + (size_t)(m0 + srow) * DMODEL + scol;
  const h16* a1 = a0 + (size_t)64 * DMODEL;
  const h16* b0 = Bt + (size_t)(n0 + srow) * DMODEL + scol;
  const h16* b1 = b0 + (size_t)64 * DMODEL;
  h16* alds0 = Al + wv * 512;
  h16* alds1 = Al + 2048 + wv * 512;
  h16* blds0 = Bl + wv * 512;
  h16* blds1 = Bl + 2048 + wv * 512;

  for (int k0 = 0; k0 < DMODEL; k0 += 32) {
    __syncthreads();
    gll16(alds0, a0 + k0);
    gll16(alds1, a1 + k0);
    gll16(blds0, b0 + k0);
    gll16(blds1, b1 + k0);
    __syncthreads();
    h16x8 af[4], bfr[4];
#pragma unroll
    for (int i = 0; i < 4; ++i) {
      af[i]  = *(const h16x8*)(Al + (wm + i * 16 + lr) * 32 + lk);
      bfr[i] = *(const h16x8*)(Bl + (wn + i * 16 + lr) * 32 + lk);
    }
#pragma unroll
    for (int i = 0; i < 4; ++i)
#pragma unroll
      for (int j = 0; j < 4; ++j)
        acc[i][j] = __builtin_amdgcn_mfma_f32_16x16x32_f16(af[i], bfr[j], acc[i][j], 0, 0, 0);
  }
}

// ----------------------------------------------------------------- qkv ----
__global__ __launch_bounds__(256, 2) void qkv_kernel(
    const h16* __restrict__ xb,
    const h16* __restrict__ wqb, const h16* __restrict__ wkb, const h16* __restrict__ wvb,
    const float* __restrict__ ctab, const float* __restrict__ stab,
    h16* __restrict__ Qb, h16* __restrict__ Kb, h16* __restrict__ Vt) {
  __shared__ h16 Al[128 * 32], Bl[128 * 32];
  const int which = blockIdx.z;
  const h16* W = (which == 0) ? wqb : (which == 1) ? wkb : wvb;
  const int m0 = blockIdx.x * 128, n0 = blockIdx.y * 128;
  f32x4 acc[4][4];
  const f32x4 zero4 = {0.f, 0.f, 0.f, 0.f};
#pragma unroll
  for (int i = 0; i < 4; ++i)
#pragma unroll
    for (int j = 0; j < 4; ++j) acc[i][j] = zero4;

  gemm128_bt(xb, W, m0, n0, Al, Bl, acc);

  const int lane = threadIdx.x & 63, wv = threadIdx.x >> 6;
  const int wm = (wv >> 1) * 64, wn = (wv & 1) * 64;
  const int lr4 = ((lane >> 4) << 2), lc = lane & 15;
  if (which == 2) {
    // V stored transposed [B][H][D][T]; r is contiguous in t -> h16x4 store.
#pragma unroll
    for (int i = 0; i < 4; ++i) {
      const int m = m0 + wm + i * 16 + lr4;
      const int b = m >> 11, t = m & (SEQT - 1);
#pragma unroll
      for (int j = 0; j < 4; ++j) {
        const int n = n0 + wn + j * 16 + lc;
        const int h = n >> 6, d = n & 63;
        h16x4 o4;
#pragma unroll
        for (int r = 0; r < 4; ++r) o4[r] = (h16)acc[i][j][r];
        *(h16x4*)&Vt[((size_t)(b * NHEADS + h) * DKH + d) * SEQT + t] = o4;
      }
    }
  } else {
#pragma unroll
    for (int i = 0; i < 4; ++i) {
#pragma unroll
      for (int j = 0; j < 4; ++j) {
        const int n = n0 + wn + j * 16 + lc;
        const int h = n >> 6, d = n & 63;
#pragma unroll
        for (int r = 0; r < 4; ++r) {
          const int m = m0 + wm + i * 16 + lr4 + r;
          const int b = m >> 11, t = m & (SEQT - 1);
          float v = acc[i][j][r];
          float pv = __shfl_xor(v, 1);
          const int fi = d >> 1;
          float c = ctab[t * 32 + fi], s = stab[t * 32 + fi];
          float res = (d & 1) ? (v * c + pv * s) : (v * c - pv * s);
          if (which == 0) res *= QSCALE;   // fold sm_scale*log2e into Q
          h16* dst = (which == 0) ? Qb : Kb;
          dst[((size_t)(b * NHEADS + h) * SEQT + t) * DKH + d] = (h16)res;
        }
      }
    }
  }
}

// ---------------------------------------------------------------- attn ----
// Swapped-operand flash attention, KBLK=128, exp2 domain, defer-max,
// T14 async staging: issue next tile's global loads after QK, commit to
// LDS after the post-compute barrier (latency hides under softmax+PV).
// LDS row strides 38 / 70 dwords (== 6 mod 32 banks): measured conflict-free.
__global__ __launch_bounds__(256, 4) void attn_kernel(
    const h16* __restrict__ Qb, const h16* __restrict__ Kb,
    const h16* __restrict__ Vt, h16* __restrict__ Mg) {
  __shared__ h16 Kl[128][76];       // [key][d]  152B rows: 38 dw == 6 mod 32
  __shared__ h16 Vl[64][140];       // [d][key]  280B rows: 70 dw == 6 mod 32
  const int i = blockIdx.x;
  const int qt = (i & 1) ? (31 - (i >> 1)) : (i >> 1);   // work pairing
  const int bh = blockIdx.y;
  const int b = bh >> 4, h = bh & 15;
  const int tid = threadIdx.x, lane = tid & 63, wv = tid >> 6;
  const int lr = lane & 15, lg = lane >> 4;
  const int q0 = qt * 64;
  const int qbase = q0 + wv * 16;
  const int q = qbase + lr;               // this lane's q-row
  const h16* Qp = Qb + ((size_t)bh * SEQT + qbase) * DKH;
  const h16* Kp = Kb + (size_t)bh * SEQT * DKH;
  const h16* Vp = Vt + (size_t)bh * DKH * SEQT;

  // Q as B-fragment of S^T = K·Q^T : col=q(lr), k=d(kk*32+lg*8+j)
  h16x8 qf[2];
#pragma unroll
  for (int kk = 0; kk < 2; ++kk)
    qf[kk] = *(const h16x8*)(Qp + lr * DKH + kk * 32 + lg * 8);

  float mrow = -3.0e38f, lsum = 0.f;
  f32x4 o[4];
  const f32x4 zero4 = {0.f, 0.f, 0.f, 0.f};
#pragma unroll
  for (int di = 0; di < 4; ++di) o[di] = zero4;

  const int sr = tid >> 2, sc = (tid & 3) * 16;
  const int nkt = (qt >> 1) + 1;

  uint4 ka[4], va[4];   // prefetch registers (static indexing only)
#define ISSUE(k0_)                                                              \
  {                                                                             \
    const h16* kb_ = Kp + (size_t)(k0_) * DKH;                                  \
    const h16* vb_ = Vp + (k0_);                                                \
    ka[0] = *(const uint4*)(kb_ + (size_t)sr * DKH + sc);                       \
    ka[1] = *(const uint4*)(kb_ + (size_t)sr * DKH + sc + 8);                   \
    ka[2] = *(const uint4*)(kb_ + (size_t)(64 + sr) * DKH + sc);                \
    ka[3] = *(const uint4*)(kb_ + (size_t)(64 + sr) * DKH + sc + 8);            \
    va[0] = *(const uint4*)(vb_ + (size_t)sr * SEQT + sc);                      \
    va[1] = *(const uint4*)(vb_ + (size_t)sr * SEQT + sc + 8);                  \
    va[2] = *(const uint4*)(vb_ + (size_t)sr * SEQT + 64 + sc);                 \
    va[3] = *(const uint4*)(vb_ + (size_t)sr * SEQT + 64 + sc + 8);             \
  }
#define COMMIT()                                                                \
  {                                                                             \
    *(uint4*)&Kl[sr][sc]          = ka[0];                                      \
    *(uint4*)&Kl[sr][sc + 8]      = ka[1];                                      \
    *(uint4*)&Kl[64 + sr][sc]     = ka[2];                                      \
    *(uint4*)&Kl[64 + sr][sc + 8] = ka[3];                                      \
    *(uint4*)&Vl[sr][sc]          = va[0];                                      \
    *(uint4*)&Vl[sr][sc + 8]      = va[1];                                      \
    *(uint4*)&Vl[sr][64 + sc]     = va[2];                                      \
    *(uint4*)&Vl[sr][64 + sc + 8] = va[3];                                      \
  }

  // prologue: stage tile 0
  ISSUE(0);
  COMMIT();               // compiler inserts vmcnt waits before ds_write
  __syncthreads();

  for (int kt = 0; kt < nkt; ++kt) {
    const int k0 = kt * 128;

    // S^T tile: lane holds score(q, key = k0 + ni*16 + lg*4 + r)
    f32x4 s[8];
    __builtin_amdgcn_s_setprio(1);
#pragma unroll
    for (int ni = 0; ni < 8; ++ni) {
      s[ni] = zero4;
#pragma unroll
      for (int kk = 0; kk < 2; ++kk) {
        h16x8 kf = *(const h16x8*)&Kl[ni * 16 + lr][kk * 32 + lg * 8];
        s[ni] = __builtin_amdgcn_mfma_f32_16x16x32_f16(kf, qf[kk], s[ni], 0, 0, 0);
      }
    }
    __builtin_amdgcn_s_setprio(0);

    // issue NEXT tile's loads now; latency hides under softmax + PV
    const bool more = (kt + 1 < nkt);
    if (more) ISSUE(k0 + 128);

    // causal mask only on the last (diagonal) tile; scale pre-folded into Q
    if (kt == nkt - 1) {
#pragma unroll
      for (int ni = 0; ni < 8; ++ni)
#pragma unroll
        for (int r = 0; r < 4; ++r) {
          const int key = k0 + ni * 16 + lg * 4 + r;
          if (key > q) s[ni][r] = -3.0e38f;
        }
    }

    // online softmax in exp2 domain with defer-max (THR = 11 ~ 8 nats)
    float mx = s[0][0];
#pragma unroll
    for (int ni = 0; ni < 8; ++ni)
#pragma unroll
      for (int r = 0; r < 4; ++r) mx = fmaxf(mx, s[ni][r]);
    mx = fmaxf(mx, __shfl_xor(mx, 16));
    mx = fmaxf(mx, __shfl_xor(mx, 32));
    if (mx > mrow + 11.0f) {
      const float mnew = fmaxf(mrow, mx);
      const float scl = exp2f(mrow - mnew);
      mrow = mnew;
      lsum *= scl;
#pragma unroll
      for (int di = 0; di < 4; ++di)
#pragma unroll
        for (int r = 0; r < 4; ++r) o[di][r] *= scl;
    }
    float rs = 0.f;
#pragma unroll
    for (int ni = 0; ni < 8; ++ni)
#pragma unroll
      for (int r = 0; r < 4; ++r) {
        float p = exp2f(s[ni][r] - mrow);
        s[ni][r] = p;
        rs += p;
      }
    rs += __shfl_xor(rs, 16);
    rs += __shfl_xor(rs, 32);
    lsum += rs;

    // PV: O^T = V^T · P^T via 16x16x16; P stays in registers.
    __builtin_amdgcn_s_setprio(1);
#pragma unroll
    for (int ni = 0; ni < 8; ++ni) {
      h16x2 plo = pkrtz(s[ni][0], s[ni][1]);
      h16x2 phi = pkrtz(s[ni][2], s[ni][3]);
      h16x4 pb; pb[0] = plo[0]; pb[1] = plo[1]; pb[2] = phi[0]; pb[3] = phi[1];
#pragma unroll
      for (int di = 0; di < 4; ++di) {
        h16x4 vv = *(const h16x4*)&Vl[di * 16 + lr][ni * 16 + lg * 4];
        o[di] = __builtin_amdgcn_mfma_f32_16x16x16f16(vv, pb, o[di], 0, 0, 0);
      }
    }
    __builtin_amdgcn_s_setprio(0);

    if (more) {
      __syncthreads();    // all waves done reading LDS tile kt
      COMMIT();           // vmcnt waits inserted automatically
      __syncthreads();    // writes visible
    }
  }
#undef ISSUE
#undef COMMIT

  // epilogue: normalize, bounce through LDS (reuse Kl) for coalesced write
  __syncthreads();
  const float inv = 1.0f / lsum;
#pragma unroll
  for (int di = 0; di < 4; ++di) {
    h16x2 lo = pkrtz(o[di][0] * inv, o[di][1] * inv);
    h16x2 hi = pkrtz(o[di][2] * inv, o[di][3] * inv);
    h16x4 o4; o4[0] = lo[0]; o4[1] = lo[1]; o4[2] = hi[0]; o4[3] = hi[1];
    *(h16x4*)&Kl[wv * 16 + lr][di * 16 + lg * 4] = o4;
  }
  __syncthreads();
  {
    const int row = tid >> 2, c0 = (tid & 3) * 16;
    h16* dst = Mg + ((size_t)(b * SEQT + q0 + row)) * DMODEL + h * DKH + c0;
    *(uint4*)dst       = *(const uint4*)&Kl[row][c0];
    *(uint4*)(dst + 8) = *(const uint4*)&Kl[row][c0 + 8];
  }
}

// ---------------------------------------------------------------- proj ----
__global__ __launch_bounds__(256, 2) void proj_kernel(
    const h16* __restrict__ Mg, const h16* __restrict__ wob, float* __restrict__ out) {
  __shared__ h16 Al[128 * 32], Bl[128 * 32];
  const int m0 = blockIdx.x * 128, n0 = blockIdx.y * 128;
  f32x4 acc[4][4];
  const f32x4 zero4 = {0.f, 0.f, 0.f, 0.f};
#pragma unroll
  for (int i = 0; i < 4; ++i)
#pragma unroll
    for (int j = 0; j < 4; ++j) acc[i][j] = zero4;

  gemm128_bt(Mg, wob, m0, n0, Al, Bl, acc);

  const int lane = threadIdx.x & 63, wv = threadIdx.x >> 6;
  const int wm = (wv >> 1) * 64, wn = (wv & 1) * 64;
  const int lr4 = ((lane >> 4) << 2), lc = lane & 15;
#pragma unroll
  for (int i = 0; i < 4; ++i)
#pragma unroll
    for (int j = 0; j < 4; ++j) {
      const int n = n0 + wn + j * 16 + lc;
#pragma unroll
      for (int r = 0; r < 4; ++r) {
        const int m = m0 + wm + i * 16 + lr4 + r;
        out[(size_t)m * DMODEL + n] = acc[i][j][r];
      }
    }
}

// -------------------------------------------------------------- launch ----
extern "C" void kernel_launch(void* const* d_in, const int* in_sizes, int n_in,
                              void* d_out, int out_size, void* d_ws, size_t ws_size,
                              hipStream_t stream) {
  (void)in_sizes; (void)n_in; (void)out_size; (void)ws_size;
  const float* x  = (const float*)d_in[0];
  const float* Wq = (const float*)d_in[1];
  const float* Wk = (const float*)d_in[2];
  const float* Wv = (const float*)d_in[3];
  const float* Wo = (const float*)d_in[4];
  float* out = (float*)d_out;

  char* w = (char*)d_ws;
  h16* xb  = (h16*)w; w += (size_t)MTOT * DMODEL * 2;
  h16* wqb = (h16*)w; w += (size_t)DMODEL * DMODEL * 2;
  h16* wkb = (h16*)w; w += (size_t)DMODEL * DMODEL * 2;
  h16* wvb = (h16*)w; w += (size_t)DMODEL * DMODEL * 2;
  h16* wob = (h16*)w; w += (size_t)DMODEL * DMODEL * 2;
  h16* Qb  = (h16*)w; w += (size_t)MTOT * DMODEL * 2;
  h16* Kb  = (h16*)w; w += (size_t)MTOT * DMODEL * 2;
  h16* Vt  = (h16*)w; w += (size_t)MTOT * DMODEL * 2;
  h16* Mg  = (h16*)w; w += (size_t)MTOT * DMODEL * 2;
  float* ctab = (float*)w; w += (size_t)SEQT * 32 * 4;
  float* stab = (float*)w; w += (size_t)SEQT * 32 * 4;

  prep_kernel<<<1024, 256, 0, stream>>>((const float4*)x, (const float4*)Wq, (const float4*)Wk,
                                        (const float4*)Wv, (const float4*)Wo,
                                        (h16x4*)xb, (h16x4*)wqb, (h16x4*)wkb, (h16x4*)wvb,
                                        (h16x4*)wob, ctab, stab);
  qkv_kernel<<<dim3(32, 8, 3), 256, 0, stream>>>(xb, wqb, wkb, wvb, ctab, stab, Qb, Kb, Vt);
  attn_kernel<<<dim3(32, 32), 256, 0, stream>>>(Qb, Kb, Vt, Mg);
  proj_kernel<<<dim3(32, 8), 256, 0, stream>>>(Mg, wob, out);
}

// Round 7
// 153.145 us; speedup vs baseline: 1.4422x; 1.4422x over previous
//
#include <hip/hip_runtime.h>
#include <cstdint>
#include <cstddef>

#define DMODEL 1024
#define NHEADS 16
#define DKH    64
#define SEQT   2048
#define NBATCH 2
#define MTOT   (NBATCH*SEQT)   // 4096

// 0.125 * log2(e): folds sm_scale and the exp->exp2 conversion into Q.
#define QSCALE 0.1803368801111204f

using h16   = _Float16;
using h16x2 = __attribute__((ext_vector_type(2))) h16;
using h16x4 = __attribute__((ext_vector_type(4))) h16;
using h16x8 = __attribute__((ext_vector_type(8))) h16;
using f32x4 = __attribute__((ext_vector_type(4))) float;
using fp16x2_native = __attribute__((ext_vector_type(2))) __fp16;

using as1_void = __attribute__((address_space(1))) void;
using as3_void = __attribute__((address_space(3))) void;

__device__ __forceinline__ void gll16(void* lds, const void* g) {
  __builtin_amdgcn_global_load_lds((const as1_void*)g, (as3_void*)lds, 16, 0, 0);
}

__device__ __forceinline__ h16x2 pkrtz(float a, float b) {
  fp16x2_native t = __builtin_amdgcn_cvt_pkrtz(a, b);
  h16x2 r; r[0] = (h16)t[0]; r[1] = (h16)t[1]; return r;
}

__device__ __forceinline__ h16x4 cvt4(const float4 v) {
  h16x4 o; o[0] = (h16)v.x; o[1] = (h16)v.y; o[2] = (h16)v.z; o[3] = (h16)v.w; return o;
}

// ---------------------------------------------------------------- prep ----
__global__ void prep_kernel(const float4* __restrict__ x,
                            const float4* __restrict__ Wq, const float4* __restrict__ Wk,
                            const float4* __restrict__ Wv, const float4* __restrict__ Wo,
                            h16x4* __restrict__ xb,
                            h16x4* __restrict__ wqb, h16x4* __restrict__ wkb,
                            h16x4* __restrict__ wvb, h16x4* __restrict__ wob,
                            float* __restrict__ ctab, float* __restrict__ stab) {
  const int tid  = blockIdx.x * blockDim.x + threadIdx.x;
  const int nthr = gridDim.x * blockDim.x;
  const int NX4 = MTOT * DMODEL / 4;
  const int NW4 = DMODEL * DMODEL / 4;
  for (int i = tid; i < NX4; i += nthr) xb[i] = cvt4(x[i]);
  for (int i = tid; i < NW4; i += nthr) {
    wqb[i] = cvt4(Wq[i]);
    wkb[i] = cvt4(Wk[i]);
    wvb[i] = cvt4(Wv[i]);
    wob[i] = cvt4(Wo[i]);
  }
  for (int i = tid; i < SEQT * 32; i += nthr) {
    const int t = i >> 5, fi = i & 31;
    float inv = __expf(-0.28782313662425575f * (float)fi);
    float ang = (float)t * inv;
    float s, c;
    sincosf(ang, &s, &c);
    ctab[i] = c; stab[i] = s;
  }
}

// --------------------------------------------------- 128x128 B^T GEMM ----
__device__ __forceinline__ void gemm128_bt(const h16* __restrict__ A, const h16* __restrict__ Bt,
                                           int m0, int n0, h16* Al, h16* Bl, f32x4 acc[4][4]) {
  const int tid  = threadIdx.x;
  const int lane = tid & 63;
  const int wv   = tid >> 6;
  const int wm = (wv >> 1) * 64, wn = (wv & 1) * 64;
  const int lr = lane & 15, lk = (lane >> 4) * 8;
  const int srow = tid >> 2, scol = (tid & 3) * 8;
  const h16* a0 = A  + (size_t)(m0 + srow) * DMODEL + scol;
  const h16* a1 = a0 + (size_t)64 * DMODEL;
  const h16* b0 = Bt + (size_t)(n0 + srow) * DMODEL + scol;
  const h16* b1 = b0 + (size_t)64 * DMODEL;
  h16* alds0 = Al + wv * 512;
  h16* alds1 = Al + 2048 + wv * 512;
  h16* blds0 = Bl + wv * 512;
  h16* blds1 = Bl + 2048 + wv * 512;

  for (int k0 = 0; k0 < DMODEL; k0 += 32) {
    __syncthreads();
    gll16(alds0, a0 + k0);
    gll16(alds1, a1 + k0);
    gll16(blds0, b0 + k0);
    gll16(blds1, b1 + k0);
    __syncthreads();
    h16x8 af[4], bfr[4];
#pragma unroll
    for (int i = 0; i < 4; ++i) {
      af[i]  = *(const h16x8*)(Al + (wm + i * 16 + lr) * 32 + lk);
      bfr[i] = *(const h16x8*)(Bl + (wn + i * 16 + lr) * 32 + lk);
    }
#pragma unroll
    for (int i = 0; i < 4; ++i)
#pragma unroll
      for (int j = 0; j < 4; ++j)
        acc[i][j] = __builtin_amdgcn_mfma_f32_16x16x32_f16(af[i], bfr[j], acc[i][j], 0, 0, 0);
  }
}

// ----------------------------------------------------------------- qkv ----
__global__ __launch_bounds__(256, 2) void qkv_kernel(
    const h16* __restrict__ xb,
    const h16* __restrict__ wqb, const h16* __restrict__ wkb, const h16* __restrict__ wvb,
    const float* __restrict__ ctab, const float* __restrict__ stab,
    h16* __restrict__ Qb, h16* __restrict__ Kb, h16* __restrict__ Vt) {
  __shared__ h16 Al[128 * 32], Bl[128 * 32];
  const int which = blockIdx.z;
  const h16* W = (which == 0) ? wqb : (which == 1) ? wkb : wvb;
  const int m0 = blockIdx.x * 128, n0 = blockIdx.y * 128;
  f32x4 acc[4][4];
  const f32x4 zero4 = {0.f, 0.f, 0.f, 0.f};
#pragma unroll
  for (int i = 0; i < 4; ++i)
#pragma unroll
    for (int j = 0; j < 4; ++j) acc[i][j] = zero4;

  gemm128_bt(xb, W, m0, n0, Al, Bl, acc);

  const int lane = threadIdx.x & 63, wv = threadIdx.x >> 6;
  const int wm = (wv >> 1) * 64, wn = (wv & 1) * 64;
  const int lr4 = ((lane >> 4) << 2), lc = lane & 15;
  if (which == 2) {
    // V stored transposed [B][H][D][T]; r is contiguous in t -> h16x4 store.
#pragma unroll
    for (int i = 0; i < 4; ++i) {
      const int m = m0 + wm + i * 16 + lr4;
      const int b = m >> 11, t = m & (SEQT - 1);
#pragma unroll
      for (int j = 0; j < 4; ++j) {
        const int n = n0 + wn + j * 16 + lc;
        const int h = n >> 6, d = n & 63;
        h16x4 o4;
#pragma unroll
        for (int r = 0; r < 4; ++r) o4[r] = (h16)acc[i][j][r];
        *(h16x4*)&Vt[((size_t)(b * NHEADS + h) * DKH + d) * SEQT + t] = o4;
      }
    }
  } else {
#pragma unroll
    for (int i = 0; i < 4; ++i) {
#pragma unroll
      for (int j = 0; j < 4; ++j) {
        const int n = n0 + wn + j * 16 + lc;
        const int h = n >> 6, d = n & 63;
#pragma unroll
        for (int r = 0; r < 4; ++r) {
          const int m = m0 + wm + i * 16 + lr4 + r;
          const int b = m >> 11, t = m & (SEQT - 1);
          float v = acc[i][j][r];
          float pv = __shfl_xor(v, 1);
          const int fi = d >> 1;
          float c = ctab[t * 32 + fi], s = stab[t * 32 + fi];
          float res = (d & 1) ? (v * c + pv * s) : (v * c - pv * s);
          if (which == 0) res *= QSCALE;   // fold sm_scale*log2e into Q
          h16* dst = (which == 0) ? Qb : Kb;
          dst[((size_t)(b * NHEADS + h) * SEQT + t) * DKH + d] = (h16)res;
        }
      }
    }
  }
}

// ---------------------------------------------------------------- attn ----
// Swapped-operand flash attention, KBLK=128, exp2 domain, defer-max.
// T3 2-phase pipeline: global_load_lds double-buffer (zero VGPR cost),
// one barrier per tile; the barrier's vmcnt(0) drain lands after ~600cy
// of compute so the prefetch is free. Linear LDS tiles + XOR granule
// swizzle (g ^= row&7, 16B granules) applied to BOTH the per-lane global
// source address and the LDS read address (rule #21 both-sides involution).
__global__ __launch_bounds__(256, 2) void attn_kernel(
    const h16* __restrict__ Qb, const h16* __restrict__ Kb,
    const h16* __restrict__ Vt, h16* __restrict__ Mg) {
  __shared__ h16 KLDS[2 * 8192];    // 2 x [128 keys][64 d], 128B rows, linear
  __shared__ h16 VLDS[2 * 8192];    // 2 x [64 d][128 keys], 256B rows, linear
  const int blk = blockIdx.x;
  const int qt = (blk & 1) ? (31 - (blk >> 1)) : (blk >> 1);   // work pairing
  const int bh = blockIdx.y;
  const int b = bh >> 4, h = bh & 15;
  const int tid = threadIdx.x, lane = tid & 63, wv = tid >> 6;
  const int lr = lane & 15, lg = lane >> 4, lr7 = lr & 7;
  const int q0 = qt * 64;
  const int qbase = q0 + wv * 16;
  const int q = qbase + lr;               // this lane's q-row
  const h16* Qp = Qb + ((size_t)bh * SEQT + qbase) * DKH;
  const h16* Kp = Kb + (size_t)bh * SEQT * DKH;
  const h16* Vp = Vt + (size_t)bh * DKH * SEQT;

  // staging source offsets (pre-swizzled global columns; dest is linear)
  const int l8 = lane & 7, l8h = lane >> 3;     // K: 8 granules/row, 8 rows/KB
  const int l16 = lane & 15, l16h = lane >> 4;  // V: 16 granules/row, 4 rows/KB
  int koff[4], voff[4];
#pragma unroll
  for (int j = 0; j < 4; ++j) {
    // K chunk j: row = (wv*4+j)*8 + l8h, dest granule l8, src granule l8^row&7
    koff[j] = ((wv * 4 + j) * 8 + l8h) * DKH + ((l8 ^ l8h) << 3);
    // V chunk j: row = (wv*4+j)*4 + l16h, row&7 = ((j&1)<<2)+l16h
    const int r7 = ((j & 1) << 2) + l16h;
    const int gsrc = (l16 & 8) | ((l16 & 7) ^ r7);
    voff[j] = ((wv * 4 + j) * 4 + l16h) * SEQT + (gsrc << 3);
  }

  // Q as B-fragment of S^T = K·Q^T : col=q(lr), k=d(kk*32+lg*8+j)
  h16x8 qf[2];
#pragma unroll
  for (int kk = 0; kk < 2; ++kk)
    qf[kk] = *(const h16x8*)(Qp + lr * DKH + kk * 32 + lg * 8);

  float mrow = -3.0e38f, lsum = 0.f;
  f32x4 o[4];
  const f32x4 zero4 = {0.f, 0.f, 0.f, 0.f};
#pragma unroll
  for (int di = 0; di < 4; ++di) o[di] = zero4;

  const int nkt = (qt >> 1) + 1;
  int cur = 0;

  // prologue: stage tile 0 into buffer 0
  {
    h16* kl = KLDS + wv * 2048;
    h16* vl = VLDS + wv * 2048;
#pragma unroll
    for (int j = 0; j < 4; ++j) {
      gll16(kl + j * 512, Kp + koff[j]);
      gll16(vl + j * 512, Vp + voff[j]);
    }
  }
  __syncthreads();   // vmcnt(0) drain: tile 0 resident

  for (int kt = 0; kt < nkt; ++kt) {
    const int k0 = kt * 128;
    const bool more = (kt + 1 < nkt);

    // issue next tile's DMA into the other buffer; hides under compute
    if (more) {
      const int nxt = cur ^ 1;
      const h16* kg = Kp + (size_t)(k0 + 128) * DKH;
      const h16* vg = Vp + (k0 + 128);
      h16* kl = KLDS + nxt * 8192 + wv * 2048;
      h16* vl = VLDS + nxt * 8192 + wv * 2048;
#pragma unroll
      for (int j = 0; j < 4; ++j) {
        gll16(kl + j * 512, kg + koff[j]);
        gll16(vl + j * 512, vg + voff[j]);
      }
      __builtin_amdgcn_sched_barrier(0);   // pin the DMA issue early
    }

    const h16* Kl = KLDS + cur * 8192;
    const h16* Vl = VLDS + cur * 8192;

    // S^T tile: lane holds score(q, key = k0 + ni*16 + lg*4 + r)
    f32x4 s[8];
    __builtin_amdgcn_s_setprio(1);
#pragma unroll
    for (int ni = 0; ni < 8; ++ni) {
      s[ni] = zero4;
#pragma unroll
      for (int kk = 0; kk < 2; ++kk) {
        // row = ni*16+lr (row&7 = lr7); global granule kk*4+lg, swizzled
        h16x8 kf = *(const h16x8*)(Kl + (ni * 16 + lr) * 64 + ((((kk << 2) | lg) ^ lr7) << 3));
        s[ni] = __builtin_amdgcn_mfma_f32_16x16x32_f16(kf, qf[kk], s[ni], 0, 0, 0);
      }
    }
    __builtin_amdgcn_s_setprio(0);

    // causal mask only on the last (diagonal) tile; scale pre-folded into Q
    if (kt == nkt - 1) {
#pragma unroll
      for (int ni = 0; ni < 8; ++ni)
#pragma unroll
        for (int r = 0; r < 4; ++r) {
          const int key = k0 + ni * 16 + lg * 4 + r;
          if (key > q) s[ni][r] = -3.0e38f;
        }
    }

    // online softmax in exp2 domain with defer-max (THR = 11 ~ 8 nats)
    float mx = s[0][0];
#pragma unroll
    for (int ni = 0; ni < 8; ++ni)
#pragma unroll
      for (int r = 0; r < 4; ++r) mx = fmaxf(mx, s[ni][r]);
    mx = fmaxf(mx, __shfl_xor(mx, 16));
    mx = fmaxf(mx, __shfl_xor(mx, 32));
    if (mx > mrow + 11.0f) {
      const float mnew = fmaxf(mrow, mx);
      const float scl = exp2f(mrow - mnew);
      mrow = mnew;
      lsum *= scl;
#pragma unroll
      for (int di = 0; di < 4; ++di)
#pragma unroll
        for (int r = 0; r < 4; ++r) o[di][r] *= scl;
    }
    float rs = 0.f;
#pragma unroll
    for (int ni = 0; ni < 8; ++ni)
#pragma unroll
      for (int r = 0; r < 4; ++r) {
        float p = exp2f(s[ni][r] - mrow);
        s[ni][r] = p;
        rs += p;
      }
    rs += __shfl_xor(rs, 16);
    rs += __shfl_xor(rs, 32);
    lsum += rs;

    // PV: O^T = V^T · P^T via 16x16x16; P stays in registers.
    __builtin_amdgcn_s_setprio(1);
#pragma unroll
    for (int ni = 0; ni < 8; ++ni) {
      h16x2 plo = pkrtz(s[ni][0], s[ni][1]);
      h16x2 phi = pkrtz(s[ni][2], s[ni][3]);
      h16x4 pb; pb[0] = plo[0]; pb[1] = plo[1]; pb[2] = phi[0]; pb[3] = phi[1];
      const int g = (ni << 1) | (lg >> 1);        // 16B granule of keys
      const int gs = (g & 8) | ((g & 7) ^ lr7);   // swizzled
#pragma unroll
      for (int di = 0; di < 4; ++di) {
        // row = di*16+lr (row&7 = lr7), 8B half = lg&1
        h16x4 vv = *(const h16x4*)(Vl + (di * 16 + lr) * 128 + (gs << 3) + ((lg & 1) << 2));
        o[di] = __builtin_amdgcn_mfma_f32_16x16x16f16(vv, pb, o[di], 0, 0, 0);
      }
    }
    __builtin_amdgcn_s_setprio(0);

    __syncthreads();   // drains prefetch vmcnt + publishes next buffer
    if (more) cur ^= 1;
  }

  // epilogue: normalize, bounce through LDS for coalesced write.
  // Bounce buffer: KLDS[cur] as [64 q][64 d] linear 128B rows, same swizzle.
  h16* bl = KLDS + cur * 8192;
  const float inv = 1.0f / lsum;
#pragma unroll
  for (int di = 0; di < 4; ++di) {
    h16x2 lo = pkrtz(o[di][0] * inv, o[di][1] * inv);
    h16x2 hi = pkrtz(o[di][2] * inv, o[di][3] * inv);
    h16x4 o4; o4[0] = lo[0]; o4[1] = lo[1]; o4[2] = hi[0]; o4[3] = hi[1];
    const int g = (di << 1) | (lg >> 1);
    *(h16x4*)(bl + (wv * 16 + lr) * 64 + (((g ^ lr7)) << 3) + ((lg & 1) << 2)) = o4;
  }
  __syncthreads();
  {
    const int row = tid >> 2, c = tid & 3, r7 = row & 7;
    h16* dst = Mg + ((size_t)(b * SEQT + q0 + row)) * DMODEL + h * DKH + c * 16;
#pragma unroll
    for (int u = 0; u < 2; ++u)
      *(uint4*)(dst + u * 8) = *(const uint4*)(bl + row * 64 + ((((c << 1) | u) ^ r7) << 3));
  }
}

// ---------------------------------------------------------------- proj ----
__global__ __launch_bounds__(256, 2) void proj_kernel(
    const h16* __restrict__ Mg, const h16* __restrict__ wob, float* __restrict__ out) {
  __shared__ h16 Al[128 * 32], Bl[128 * 32];
  const int m0 = blockIdx.x * 128, n0 = blockIdx.y * 128;
  f32x4 acc[4][4];
  const f32x4 zero4 = {0.f, 0.f, 0.f, 0.f};
#pragma unroll
  for (int i = 0; i < 4; ++i)
#pragma unroll
    for (int j = 0; j < 4; ++j) acc[i][j] = zero4;

  gemm128_bt(Mg, wob, m0, n0, Al, Bl, acc);

  const int lane = threadIdx.x & 63, wv = threadIdx.x >> 6;
  const int wm = (wv >> 1) * 64, wn = (wv & 1) * 64;
  const int lr4 = ((lane >> 4) << 2), lc = lane & 15;
#pragma unroll
  for (int i = 0; i < 4; ++i)
#pragma unroll
    for (int j = 0; j < 4; ++j) {
      const int n = n0 + wn + j * 16 + lc;
#pragma unroll
      for (int r = 0; r < 4; ++r) {
        const int m = m0 + wm + i * 16 + lr4 + r;
        out[(size_t)m * DMODEL + n] = acc[i][j][r];
      }
    }
}

// -------------------------------------------------------------- launch ----
extern "C" void kernel_launch(void* const* d_in, const int* in_sizes, int n_in,
                              void* d_out, int out_size, void* d_ws, size_t ws_size,
                              hipStream_t stream) {
  (void)in_sizes; (void)n_in; (void)out_size; (void)ws_size;
  const float* x  = (const float*)d_in[0];
  const float* Wq = (const float*)d_in[1];
  const float* Wk = (const float*)d_in[2];
  const float* Wv = (const float*)d_in[3];
  const float* Wo = (const float*)d_in[4];
  float* out = (float*)d_out;

  char* w = (char*)d_ws;
  h16* xb  = (h16*)w; w += (size_t)MTOT * DMODEL * 2;
  h16* wqb = (h16*)w; w += (size_t)DMODEL * DMODEL * 2;
  h16* wkb = (h16*)w; w += (size_t)DMODEL * DMODEL * 2;
  h16* wvb = (h16*)w; w += (size_t)DMODEL * DMODEL * 2;
  h16* wob = (h16*)w; w += (size_t)DMODEL * DMODEL * 2;
  h16* Qb  = (h16*)w; w += (size_t)MTOT * DMODEL * 2;
  h16* Kb  = (h16*)w; w += (size_t)MTOT * DMODEL * 2;
  h16* Vt  = (h16*)w; w += (size_t)MTOT * DMODEL * 2;
  h16* Mg  = (h16*)w; w += (size_t)MTOT * DMODEL * 2;
  float* ctab = (float*)w; w += (size_t)SEQT * 32 * 4;
  float* stab = (float*)w; w += (size_t)SEQT * 32 * 4;

  prep_kernel<<<1024, 256, 0, stream>>>((const float4*)x, (const float4*)Wq, (const float4*)Wk,
                                        (const float4*)Wv, (const float4*)Wo,
                                        (h16x4*)xb, (h16x4*)wqb, (h16x4*)wkb, (h16x4*)wvb,
                                        (h16x4*)wob, ctab, stab);
  qkv_kernel<<<dim3(32, 8, 3), 256, 0, stream>>>(xb, wqb, wkb, wvb, ctab, stab, Qb, Kb, Vt);
  attn_kernel<<<dim3(32, 32), 256, 0, stream>>>(Qb, Kb, Vt, Mg);
  proj_kernel<<<dim3(32, 8), 256, 0, stream>>>(Mg, wob, out);
}

// Round 8
// 115.415 us; speedup vs baseline: 1.9136x; 1.3269x over previous
//
#include <hip/hip_runtime.h>
#include <cstdint>
#include <cstddef>

#define DMODEL 1024
#define NHEADS 16
#define DKH    64
#define SEQT   2048
#define NBATCH 2
#define MTOT   (NBATCH*SEQT)   // 4096

// 0.125 * log2(e): folds sm_scale and the exp->exp2 conversion into Q.
#define QSCALE 0.1803368801111204f

using h16   = _Float16;
using h16x2 = __attribute__((ext_vector_type(2))) h16;
using h16x4 = __attribute__((ext_vector_type(4))) h16;
using h16x8 = __attribute__((ext_vector_type(8))) h16;
using f32x4 = __attribute__((ext_vector_type(4))) float;
using fp16x2_native = __attribute__((ext_vector_type(2))) __fp16;

using as1_void = __attribute__((address_space(1))) void;
using as3_void = __attribute__((address_space(3))) void;

__device__ __forceinline__ void gll16(void* lds, const void* g) {
  __builtin_amdgcn_global_load_lds((const as1_void*)g, (as3_void*)lds, 16, 0, 0);
}

__device__ __forceinline__ h16x2 pkrtz(float a, float b) {
  fp16x2_native t = __builtin_amdgcn_cvt_pkrtz(a, b);
  h16x2 r; r[0] = (h16)t[0]; r[1] = (h16)t[1]; return r;
}

__device__ __forceinline__ h16x4 cvt4(const float4 v) {
  h16x4 o; o[0] = (h16)v.x; o[1] = (h16)v.y; o[2] = (h16)v.z; o[3] = (h16)v.w; return o;
}

// ---------------------------------------------------------------- prep ----
__global__ void prep_kernel(const float4* __restrict__ x,
                            const float4* __restrict__ Wq, const float4* __restrict__ Wk,
                            const float4* __restrict__ Wv, const float4* __restrict__ Wo,
                            h16x4* __restrict__ xb,
                            h16x4* __restrict__ wqb, h16x4* __restrict__ wkb,
                            h16x4* __restrict__ wvb, h16x4* __restrict__ wob,
                            float* __restrict__ ctab, float* __restrict__ stab) {
  const int tid  = blockIdx.x * blockDim.x + threadIdx.x;
  const int nthr = gridDim.x * blockDim.x;
  const int NX4 = MTOT * DMODEL / 4;
  const int NW4 = DMODEL * DMODEL / 4;
  for (int i = tid; i < NX4; i += nthr) xb[i] = cvt4(x[i]);
  for (int i = tid; i < NW4; i += nthr) {
    wqb[i] = cvt4(Wq[i]);
    wkb[i] = cvt4(Wk[i]);
    wvb[i] = cvt4(Wv[i]);
    wob[i] = cvt4(Wo[i]);
  }
  for (int i = tid; i < SEQT * 32; i += nthr) {
    const int t = i >> 5, fi = i & 31;
    float inv = __expf(-0.28782313662425575f * (float)fi);
    float ang = (float)t * inv;
    float s, c;
    sincosf(ang, &s, &c);
    ctab[i] = c; stab[i] = s;
  }
}

// --------------------------------------------------- 128x128 B^T GEMM ----
__device__ __forceinline__ void gemm128_bt(const h16* __restrict__ A, const h16* __restrict__ Bt,
                                           int m0, int n0, h16* Al, h16* Bl, f32x4 acc[4][4]) {
  const int tid  = threadIdx.x;
  const int lane = tid & 63;
  const int wv   = tid >> 6;
  const int wm = (wv >> 1) * 64, wn = (wv & 1) * 64;
  const int lr = lane & 15, lk = (lane >> 4) * 8;
  const int srow = tid >> 2, scol = (tid & 3) * 8;
  const h16* a0 = A  + (size_t)(m0 + srow) * DMODEL + scol;
  const h16* a1 = a0 + (size_t)64 * DMODEL;
  const h16* b0 = Bt + (size_t)(n0 + srow) * DMODEL + scol;
  const h16* b1 = b0 + (size_t)64 * DMODEL;
  h16* alds0 = Al + wv * 512;
  h16* alds1 = Al + 2048 + wv * 512;
  h16* blds0 = Bl + wv * 512;
  h16* blds1 = Bl + 2048 + wv * 512;

  for (int k0 = 0; k0 < DMODEL; k0 += 32) {
    __syncthreads();
    gll16(alds0, a0 + k0);
    gll16(alds1, a1 + k0);
    gll16(blds0, b0 + k0);
    gll16(blds1, b1 + k0);
    __syncthreads();
    h16x8 af[4], bfr[4];
#pragma unroll
    for (int i = 0; i < 4; ++i) {
      af[i]  = *(const h16x8*)(Al + (wm + i * 16 + lr) * 32 + lk);
      bfr[i] = *(const h16x8*)(Bl + (wn + i * 16 + lr) * 32 + lk);
    }
#pragma unroll
    for (int i = 0; i < 4; ++i)
#pragma unroll
      for (int j = 0; j < 4; ++j)
        acc[i][j] = __builtin_amdgcn_mfma_f32_16x16x32_f16(af[i], bfr[j], acc[i][j], 0, 0, 0);
  }
}

// ----------------------------------------------------------------- qkv ----
__global__ __launch_bounds__(256, 2) void qkv_kernel(
    const h16* __restrict__ xb,
    const h16* __restrict__ wqb, const h16* __restrict__ wkb, const h16* __restrict__ wvb,
    const float* __restrict__ ctab, const float* __restrict__ stab,
    h16* __restrict__ Qb, h16* __restrict__ Kb, h16* __restrict__ Vt) {
  __shared__ h16 Al[128 * 32], Bl[128 * 32];
  const int which = blockIdx.z;
  const h16* W = (which == 0) ? wqb : (which == 1) ? wkb : wvb;
  const int m0 = blockIdx.x * 128, n0 = blockIdx.y * 128;
  f32x4 acc[4][4];
  const f32x4 zero4 = {0.f, 0.f, 0.f, 0.f};
#pragma unroll
  for (int i = 0; i < 4; ++i)
#pragma unroll
    for (int j = 0; j < 4; ++j) acc[i][j] = zero4;

  gemm128_bt(xb, W, m0, n0, Al, Bl, acc);

  const int lane = threadIdx.x & 63, wv = threadIdx.x >> 6;
  const int wm = (wv >> 1) * 64, wn = (wv & 1) * 64;
  const int lr4 = ((lane >> 4) << 2), lc = lane & 15;
  if (which == 2) {
    // V stored transposed [B][H][D][T]; r is contiguous in t -> h16x4 store.
#pragma unroll
    for (int i = 0; i < 4; ++i) {
      const int m = m0 + wm + i * 16 + lr4;
      const int b = m >> 11, t = m & (SEQT - 1);
#pragma unroll
      for (int j = 0; j < 4; ++j) {
        const int n = n0 + wn + j * 16 + lc;
        const int h = n >> 6, d = n & 63;
        h16x4 o4;
#pragma unroll
        for (int r = 0; r < 4; ++r) o4[r] = (h16)acc[i][j][r];
        *(h16x4*)&Vt[((size_t)(b * NHEADS + h) * DKH + d) * SEQT + t] = o4;
      }
    }
  } else {
#pragma unroll
    for (int i = 0; i < 4; ++i) {
#pragma unroll
      for (int j = 0; j < 4; ++j) {
        const int n = n0 + wn + j * 16 + lc;
        const int h = n >> 6, d = n & 63;
#pragma unroll
        for (int r = 0; r < 4; ++r) {
          const int m = m0 + wm + i * 16 + lr4 + r;
          const int b = m >> 11, t = m & (SEQT - 1);
          float v = acc[i][j][r];
          float pv = __shfl_xor(v, 1);
          const int fi = d >> 1;
          float c = ctab[t * 32 + fi], s = stab[t * 32 + fi];
          float res = (d & 1) ? (v * c + pv * s) : (v * c - pv * s);
          if (which == 0) res *= QSCALE;   // fold sm_scale*log2e into Q
          h16* dst = (which == 0) ? Qb : Kb;
          dst[((size_t)(b * NHEADS + h) * SEQT + t) * DKH + d] = (h16)res;
        }
      }
    }
  }
}

// ---------------------------------------------------------------- attn ----
// Swapped-operand flash attention, KBLK=128, exp2 domain, defer-max.
// LDS row strides 38 / 70 dwords (== 6 mod 32 banks): measured conflict-free
// (R5). XCD-balanced work map: XCD class v (= linear%8) gets qt in
// {v, 15-v, 16+v, 31-v} -> exactly 34 tile-units per XCD (R5's pairing put
// all heavy blocks on odd XCDs: 52 vs 16 -> 3.25x imbalance, 18% occupancy).
// The (c32+w)&3 stagger mixes heavy/light within any stride-32 CU sampling.
__global__ __launch_bounds__(256, 4) void attn_kernel(
    const h16* __restrict__ Qb, const h16* __restrict__ Kb,
    const h16* __restrict__ Vt, h16* __restrict__ Mg) {
  __shared__ h16 Kl[128][76];       // [key][d]  152B rows: 38 dw == 6 mod 32
  __shared__ h16 Vl[64][140];       // [d][key]  280B rows: 70 dw == 6 mod 32
  const int linear = blockIdx.x + 32 * blockIdx.y;
  const int v   = linear & 7;        // XCD class
  const int p   = linear >> 3;       // 0..127 position within class
  const int w   = p >> 5;            // 0..3
  const int c32 = p & 31;
  const int u   = (c32 + w) & 3;
  const int bh  = c32;
  const int qt  = (u == 0) ? v : (u == 1) ? (15 - v) : (u == 2) ? (16 + v) : (31 - v);
  const int b = bh >> 4, h = bh & 15;
  const int tid = threadIdx.x, lane = tid & 63, wv = tid >> 6;
  const int lr = lane & 15, lg = lane >> 4;
  const int q0 = qt * 64;
  const int qbase = q0 + wv * 16;
  const int q = qbase + lr;               // this lane's q-row
  const h16* Qp = Qb + ((size_t)bh * SEQT + qbase) * DKH;
  const h16* Kp = Kb + (size_t)bh * SEQT * DKH;
  const h16* Vp = Vt + (size_t)bh * DKH * SEQT;

  // Q as B-fragment of S^T = K·Q^T : col=q(lr), k=d(kk*32+lg*8+j)
  h16x8 qf[2];
#pragma unroll
  for (int kk = 0; kk < 2; ++kk)
    qf[kk] = *(const h16x8*)(Qp + lr * DKH + kk * 32 + lg * 8);

  float mrow = -3.0e38f, lsum = 0.f;
  f32x4 o[4];
  const f32x4 zero4 = {0.f, 0.f, 0.f, 0.f};
#pragma unroll
  for (int di = 0; di < 4; ++di) o[di] = zero4;

  const int sr = tid >> 2, sc = (tid & 3) * 16;
  const int nkt = (qt >> 1) + 1;
  for (int kt = 0; kt < nkt; ++kt) {
    const int k0 = kt * 128;
    __syncthreads();
    // K: 128 rows x 64 cols, R3's zero-conflict pattern per 64-row half
#pragma unroll
    for (int half = 0; half < 2; ++half) {
      const int r = half * 64 + sr;
      *(uint4*)&Kl[r][sc]     = *(const uint4*)(Kp + (size_t)(k0 + r) * DKH + sc);
      *(uint4*)&Kl[r][sc + 8] = *(const uint4*)(Kp + (size_t)(k0 + r) * DKH + sc + 8);
    }
    // V: 64 rows x 128 cols, same pattern per 64-col half
#pragma unroll
    for (int half = 0; half < 2; ++half) {
      const int c = half * 64 + sc;
      *(uint4*)&Vl[sr][c]     = *(const uint4*)(Vp + (size_t)sr * SEQT + k0 + c);
      *(uint4*)&Vl[sr][c + 8] = *(const uint4*)(Vp + (size_t)sr * SEQT + k0 + c + 8);
    }
    __syncthreads();

    // S^T tile: lane holds score(q, key = k0 + ni*16 + lg*4 + r)
    f32x4 s[8];
    __builtin_amdgcn_s_setprio(1);
#pragma unroll
    for (int ni = 0; ni < 8; ++ni) {
      s[ni] = zero4;
#pragma unroll
      for (int kk = 0; kk < 2; ++kk) {
        h16x8 kf = *(const h16x8*)&Kl[ni * 16 + lr][kk * 32 + lg * 8];
        s[ni] = __builtin_amdgcn_mfma_f32_16x16x32_f16(kf, qf[kk], s[ni], 0, 0, 0);
      }
    }
    __builtin_amdgcn_s_setprio(0);

    // causal mask only on the last (diagonal) tile; scale pre-folded into Q
    if (kt == nkt - 1) {
#pragma unroll
      for (int ni = 0; ni < 8; ++ni)
#pragma unroll
        for (int r = 0; r < 4; ++r) {
          const int key = k0 + ni * 16 + lg * 4 + r;
          if (key > q) s[ni][r] = -3.0e38f;
        }
    }

    // online softmax in exp2 domain with defer-max (THR = 11 ~ 8 nats)
    float mx = s[0][0];
#pragma unroll
    for (int ni = 0; ni < 8; ++ni)
#pragma unroll
      for (int r = 0; r < 4; ++r) mx = fmaxf(mx, s[ni][r]);
    mx = fmaxf(mx, __shfl_xor(mx, 16));
    mx = fmaxf(mx, __shfl_xor(mx, 32));
    if (mx > mrow + 11.0f) {
      const float mnew = fmaxf(mrow, mx);
      const float scl = exp2f(mrow - mnew);
      mrow = mnew;
      lsum *= scl;
#pragma unroll
      for (int di = 0; di < 4; ++di)
#pragma unroll
        for (int r = 0; r < 4; ++r) o[di][r] *= scl;
    }
    float rs = 0.f;
#pragma unroll
    for (int ni = 0; ni < 8; ++ni)
#pragma unroll
      for (int r = 0; r < 4; ++r) {
        float p2 = exp2f(s[ni][r] - mrow);
        s[ni][r] = p2;
        rs += p2;
      }
    rs += __shfl_xor(rs, 16);
    rs += __shfl_xor(rs, 32);
    lsum += rs;

    // PV: O^T = V^T · P^T via 16x16x16; P stays in registers.
    __builtin_amdgcn_s_setprio(1);
#pragma unroll
    for (int ni = 0; ni < 8; ++ni) {
      h16x2 plo = pkrtz(s[ni][0], s[ni][1]);
      h16x2 phi = pkrtz(s[ni][2], s[ni][3]);
      h16x4 pb; pb[0] = plo[0]; pb[1] = plo[1]; pb[2] = phi[0]; pb[3] = phi[1];
#pragma unroll
      for (int di = 0; di < 4; ++di) {
        h16x4 va = *(const h16x4*)&Vl[di * 16 + lr][ni * 16 + lg * 4];
        o[di] = __builtin_amdgcn_mfma_f32_16x16x16f16(va, pb, o[di], 0, 0, 0);
      }
    }
    __builtin_amdgcn_s_setprio(0);
  }

  // epilogue: normalize, bounce through LDS (reuse Kl) for coalesced write
  __syncthreads();
  const float inv = 1.0f / lsum;
#pragma unroll
  for (int di = 0; di < 4; ++di) {
    h16x2 lo = pkrtz(o[di][0] * inv, o[di][1] * inv);
    h16x2 hi = pkrtz(o[di][2] * inv, o[di][3] * inv);
    h16x4 o4; o4[0] = lo[0]; o4[1] = lo[1]; o4[2] = hi[0]; o4[3] = hi[1];
    *(h16x4*)&Kl[wv * 16 + lr][di * 16 + lg * 4] = o4;
  }
  __syncthreads();
  {
    const int row = tid >> 2, c0 = (tid & 3) * 16;
    h16* dst = Mg + ((size_t)(b * SEQT + q0 + row)) * DMODEL + h * DKH + c0;
    *(uint4*)dst       = *(const uint4*)&Kl[row][c0];
    *(uint4*)(dst + 8) = *(const uint4*)&Kl[row][c0 + 8];
  }
}

// ---------------------------------------------------------------- proj ----
__global__ __launch_bounds__(256, 2) void proj_kernel(
    const h16* __restrict__ Mg, const h16* __restrict__ wob, float* __restrict__ out) {
  __shared__ h16 Al[128 * 32], Bl[128 * 32];
  const int m0 = blockIdx.x * 128, n0 = blockIdx.y * 128;
  f32x4 acc[4][4];
  const f32x4 zero4 = {0.f, 0.f, 0.f, 0.f};
#pragma unroll
  for (int i = 0; i < 4; ++i)
#pragma unroll
    for (int j = 0; j < 4; ++j) acc[i][j] = zero4;

  gemm128_bt(Mg, wob, m0, n0, Al, Bl, acc);

  const int lane = threadIdx.x & 63, wv = threadIdx.x >> 6;
  const int wm = (wv >> 1) * 64, wn = (wv & 1) * 64;
  const int lr4 = ((lane >> 4) << 2), lc = lane & 15;
#pragma unroll
  for (int i = 0; i < 4; ++i)
#pragma unroll
    for (int j = 0; j < 4; ++j) {
      const int n = n0 + wn + j * 16 + lc;
#pragma unroll
      for (int r = 0; r < 4; ++r) {
        const int m = m0 + wm + i * 16 + lr4 + r;
        out[(size_t)m * DMODEL + n] = acc[i][j][r];
      }
    }
}

// -------------------------------------------------------------- launch ----
extern "C" void kernel_launch(void* const* d_in, const int* in_sizes, int n_in,
                              void* d_out, int out_size, void* d_ws, size_t ws_size,
                              hipStream_t stream) {
  (void)in_sizes; (void)n_in; (void)out_size; (void)ws_size;
  const float* x  = (const float*)d_in[0];
  const float* Wq = (const float*)d_in[1];
  const float* Wk = (const float*)d_in[2];
  const float* Wv = (const float*)d_in[3];
  const float* Wo = (const float*)d_in[4];
  float* out = (float*)d_out;

  char* w = (char*)d_ws;
  h16* xb  = (h16*)w; w += (size_t)MTOT * DMODEL * 2;
  h16* wqb = (h16*)w; w += (size_t)DMODEL * DMODEL * 2;
  h16* wkb = (h16*)w; w += (size_t)DMODEL * DMODEL * 2;
  h16* wvb = (h16*)w; w += (size_t)DMODEL * DMODEL * 2;
  h16* wob = (h16*)w; w += (size_t)DMODEL * DMODEL * 2;
  h16* Qb  = (h16*)w; w += (size_t)MTOT * DMODEL * 2;
  h16* Kb  = (h16*)w; w += (size_t)MTOT * DMODEL * 2;
  h16* Vt  = (h16*)w; w += (size_t)MTOT * DMODEL * 2;
  h16* Mg  = (h16*)w; w += (size_t)MTOT * DMODEL * 2;
  float* ctab = (float*)w; w += (size_t)SEQT * 32 * 4;
  float* stab = (float*)w; w += (size_t)SEQT * 32 * 4;

  prep_kernel<<<1024, 256, 0, stream>>>((const float4*)x, (const float4*)Wq, (const float4*)Wk,
                                        (const float4*)Wv, (const float4*)Wo,
                                        (h16x4*)xb, (h16x4*)wqb, (h16x4*)wkb, (h16x4*)wvb,
                                        (h16x4*)wob, ctab, stab);
  qkv_kernel<<<dim3(32, 8, 3), 256, 0, stream>>>(xb, wqb, wkb, wvb, ctab, stab, Qb, Kb, Vt);
  attn_kernel<<<dim3(32, 32), 256, 0, stream>>>(Qb, Kb, Vt, Mg);
  proj_kernel<<<dim3(32, 8), 256, 0, stream>>>(Mg, wob, out);
}